// Round 21
// baseline (337.660 us; speedup 1.0000x reference)
//
#include <hip/hip_runtime.h>
#include <hip/hip_bf16.h>
#include <hip/hip_fp16.h>

#define N_    50000
#define DIM_  128
#define HEADS_ 8
#define HD_   16
#define E_    800000
#define NREL_ 2000
#define T_    200000
#define R_    50000
#define B_    10000
#define ALPHA_ 0.2f
#define INV3SQRT_ 0.029462782549439484f  // 1/(3*sqrt(128))
#define BSH_  7                          // 128 nodes per bucket
#define NB_   391                        // ceil(N_/128)
#define EPB_  2048                       // edges per block (partition kernels)
#define NBLK_ 391                        // ceil(E_/EPB_)
#define NBLK4_ 392                       // padded row length

typedef _Float16 f16x8 __attribute__((ext_vector_type(8)));
typedef __attribute__((ext_vector_type(4))) float f32x4;

__device__ __forceinline__ float hlo(unsigned u) {
    __half2 h = *(__half2*)&u; return __half2float(__low2half(h));
}
__device__ __forceinline__ float hhi(unsigned u) {
    __half2 h = *(__half2*)&u; return __half2float(__high2half(h));
}
__device__ __forceinline__ unsigned pack2h(float x, float y) {
    __half2 h = __floats2half2_rn(x, y);
    return *(unsigned*)&h;
}
__device__ __forceinline__ unsigned short h1f(float x) {
    __half h = __float2half_rn(x);
    return *(unsigned short*)&h;
}

// ---------------- A: per-(block,bucket) histogram — no atomics to global ----------------
__global__ __launch_bounds__(256) void count_mat_kernel(
        const int* __restrict__ dst0, const int* __restrict__ dst1,
        int* __restrict__ cmat) {   // [2*NB_][NBLK4_]
    __shared__ int hist[NB_];
    int blk = blockIdx.x;
    int g = (blk >= NBLK_);
    int bb = g ? blk - NBLK_ : blk;
    const int* dst = g ? dst1 : dst0;
    int t = threadIdx.x;
    for (int i = t; i < NB_; i += 256) hist[i] = 0;
    __syncthreads();
    int e0 = bb * EPB_;
    for (int i = t; i < EPB_; i += 256) {
        int e = e0 + i;
        if (e < E_) atomicAdd(&hist[dst[e] >> BSH_], 1);
    }
    __syncthreads();
    for (int i = t; i < NB_; i += 256)
        cmat[((size_t)(g * NB_ + i)) * NBLK4_ + bb] = hist[i];
}

// ---------------- B1: row totals ----------------
__global__ __launch_bounds__(256) void rowsum_kernel(const int* __restrict__ cmat, int* __restrict__ tot) {
    int p = blockIdx.x;              // [0, 2*NB_)
    int t = threadIdx.x;
    const int* rowp = cmat + (size_t)p * NBLK4_;
    int s = 0;
    for (int i = t; i < NBLK_; i += 256) s += rowp[i];
#pragma unroll
    for (int m = 1; m < 64; m <<= 1) s += __shfl_xor(s, m);
    __shared__ int ws[4];
    if ((t & 63) == 0) ws[t >> 6] = s;
    __syncthreads();
    if (t == 0) tot[p] = ws[0] + ws[1] + ws[2] + ws[3];
}

// ---------------- B2: bucket-base scan (Hillis-Steele per graph) ----------------
__global__ __launch_bounds__(1024) void bucket_scan_kernel(
        const int* __restrict__ tot, int* __restrict__ bbase /*[2][NB_+1]*/,
        int* __restrict__ row_start /*[2][N_+1]*/) {
    __shared__ int buf[2][512];
    int t = threadIdx.x;
    int g = t >> 9;
    int i = t & 511;
    buf[g][i] = (i < NB_) ? tot[g * NB_ + i] : 0;
    __syncthreads();
#pragma unroll
    for (int off = 1; off < 512; off <<= 1) {
        int v = (i >= off) ? buf[g][i - off] : 0;
        __syncthreads();
        buf[g][i] += v;
        __syncthreads();
    }
    if (i < NB_) bbase[g * (NB_ + 1) + i] = (i == 0) ? 0 : buf[g][i - 1];
    if (i == NB_) {
        bbase[g * (NB_ + 1) + NB_] = buf[g][NB_ - 1];
        row_start[(size_t)g * (N_ + 1) + N_] = buf[g][NB_ - 1];   // == E_
    }
}

// ---------------- B3: exclusive scan of each row ----------------
__global__ __launch_bounds__(256) void rowscan_kernel(const int* __restrict__ bbase, int* __restrict__ cmat) {
    __shared__ int ps[256];
    int p = blockIdx.x;              // [0, 2*NB_)
    int t = threadIdx.x;
    int* rowp = cmat + (size_t)p * NBLK4_;
    int a = (2 * t     < NBLK_) ? rowp[2 * t]     : 0;
    int b = (2 * t + 1 < NBLK_) ? rowp[2 * t + 1] : 0;
    ps[t] = a + b;
    __syncthreads();
#pragma unroll
    for (int off = 1; off < 256; off <<= 1) {
        int v = (t >= off) ? ps[t - off] : 0;
        __syncthreads();
        ps[t] += v;
        __syncthreads();
    }
    int g = p / NB_;
    int bk = p - g * NB_;
    int base = bbase[g * (NB_ + 1) + bk];
    int excl = base + ((t > 0) ? ps[t - 1] : 0);
    if (2 * t     < NBLK_) rowp[2 * t]     = excl;
    if (2 * t + 1 < NBLK_) rowp[2 * t + 1] = excl + a;
}

// ---------------- C: scatter with exact bases — LDS atomics only ----------------
__global__ __launch_bounds__(256) void part_scatter_kernel(
        const int* __restrict__ src0, const int* __restrict__ dst0,
        const int* __restrict__ src1, const int* __restrict__ dst1,
        const int* __restrict__ cmat, int* __restrict__ slab /*[2][E_]*/) {
    __shared__ int lcur[NB_];
    int blk = blockIdx.x;
    int g = (blk >= NBLK_);
    int bb = g ? blk - NBLK_ : blk;
    const int* src = g ? src1 : src0;
    const int* dst = g ? dst1 : dst0;
    int t = threadIdx.x;
    for (int i = t; i < NB_; i += 256)
        lcur[i] = cmat[((size_t)(g * NB_ + i)) * NBLK4_ + bb];
    __syncthreads();
    int e0 = bb * EPB_;
    for (int i = t; i < EPB_; i += 256) {
        int e = e0 + i;
        if (e < E_) {
            int d = dst[e], s = src[e];
            int r = atomicAdd(&lcur[d >> BSH_], 1);
            slab[(size_t)g * E_ + r] = ((d & 127) << 16) | s;
        }
    }
}

// ---------------- D: per-bucket counting sort; emits row_start + sorted_src ----------------
__global__ __launch_bounds__(256) void bucket_sort_kernel(
        const int* __restrict__ bbase, const int* __restrict__ slab,
        int* __restrict__ row_start, int* __restrict__ sorted_src) {
    __shared__ int hist[128], pfx[129], cur[128];
    int blk = blockIdx.x;             // [0, 2*NB_)
    int g = (blk >= NB_);
    int bk = g ? blk - NB_ : blk;
    int base = bbase[g * (NB_ + 1) + bk];
    int cnt  = bbase[g * (NB_ + 1) + bk + 1] - base;
    const int* sl = slab + (size_t)g * E_ + base;
    int t = threadIdx.x;
    if (t < 128) hist[t] = 0;
    __syncthreads();
    for (int i = t; i < cnt; i += 256) atomicAdd(&hist[sl[i] >> 16], 1);
    __syncthreads();
    if (t < 128) pfx[t + 1] = hist[t];
    if (t == 0) pfx[0] = 0;
    __syncthreads();
#pragma unroll
    for (int off = 1; off < 128; off <<= 1) {
        int v = (t < 128 && t >= off) ? pfx[t + 1 - off] : 0;
        __syncthreads();
        if (t < 128) pfx[t + 1] += v;
        __syncthreads();
    }
    int node0 = bk << BSH_;
    if (t < 128) {
        int node = node0 + t;
        if (node < N_) row_start[(size_t)g * (N_ + 1) + node] = base + pfx[t];
        cur[t] = 0;
    }
    __syncthreads();
    for (int i = t; i < cnt; i += 256) {
        int v = sl[i];
        int dl = v >> 16;
        int p = pfx[dl] + atomicAdd(&cur[dl], 1);
        sorted_src[(size_t)g * E_ + base + p] = v & 0xFFFF;
    }
}

// ---------------- prep: W[k][o] f32 -> Wt[o][k] f16, both layers ----------------
__global__ __launch_bounds__(256) void prep_wt_kernel(const float* __restrict__ W,
        unsigned short* __restrict__ Wt) {
    int idx = blockIdx.x * 256 + threadIdx.x;   // [0, 2*128*128)
    if (idx >= 2 * 128 * 128) return;
    int l = idx >> 14;
    int rem = idx & 16383;
    int o = rem >> 7, k = rem & 127;
    Wt[idx] = h1f(W[l * 16384 + k * 128 + o]);
}

// ---------------- MFMA gemm + fused alphas: h = x@W (f16 in, f32 acc, f16 out) ----------------
// verified layouts: a-frag A[l&15][(l>>4)*8+j]; b-frag B^T[l&15][(l>>4)*8+j];
// D: col=lane&15, row=(lane>>4)*4+reg. Wave w holds cols w*32..w*32+31 = heads 2w,2w+1.
__global__ __launch_bounds__(256) void gemm_mfma_both_kernel(
        const void* __restrict__ xsrc0, const void* __restrict__ xsrc1, int src_f32,
        const unsigned short* __restrict__ Wt /*[128][128] f16, o-major*/,
        const float* __restrict__ avs, const float* __restrict__ avd,
        unsigned short* __restrict__ hout /*[2][N][128] f16*/,
        float* __restrict__ asrc, float* __restrict__ adst, int half_grid) {
    __shared__ unsigned short xs[32][136];   // 16B-aligned rows, <=2-way bank alias
    int blk = blockIdx.x;
    int g = (blk >= half_grid);
    int bb = g ? blk - half_grid : blk;
    int nbase = bb * 32;
    int t = threadIdx.x;
    {
        int row = t >> 3, c0 = (t & 7) * 16;
        int node = nbase + row;
        if (node >= N_) node = N_ - 1;
        if (src_f32) {
            const float* x = (const float*)(g ? xsrc1 : xsrc0);
            const float4* xr = (const float4*)&x[(size_t)node * 128 + c0];
            float4 v0 = xr[0], v1 = xr[1], v2 = xr[2], v3 = xr[3];
            unsigned* dstp = (unsigned*)&xs[row][c0];
            dstp[0] = pack2h(v0.x, v0.y); dstp[1] = pack2h(v0.z, v0.w);
            dstp[2] = pack2h(v1.x, v1.y); dstp[3] = pack2h(v1.z, v1.w);
            dstp[4] = pack2h(v2.x, v2.y); dstp[5] = pack2h(v2.z, v2.w);
            dstp[6] = pack2h(v3.x, v3.y); dstp[7] = pack2h(v3.z, v3.w);
        } else {
            const unsigned short* x = (const unsigned short*)(g ? xsrc1 : xsrc0);
            uint4 v0 = *(const uint4*)&x[(size_t)node * 128 + c0];
            uint4 v1 = *(const uint4*)&x[(size_t)node * 128 + c0 + 8];
            *(uint4*)&xs[row][c0] = v0;
            *(uint4*)&xs[row][c0 + 8] = v1;
        }
    }
    __syncthreads();
    int wave = t >> 6, lane = t & 63;
    int n0 = wave * 32;
    int lr = lane & 15, lk = (lane >> 4) * 8;
    f32x4 acc00 = {0.f,0.f,0.f,0.f}, acc01 = {0.f,0.f,0.f,0.f};
    f32x4 acc10 = {0.f,0.f,0.f,0.f}, acc11 = {0.f,0.f,0.f,0.f};
#pragma unroll
    for (int ks = 0; ks < 128; ks += 32) {
        uint4 ra0 = *(const uint4*)&xs[lr][ks + lk];
        uint4 ra1 = *(const uint4*)&xs[16 + lr][ks + lk];
        uint4 rb0 = *(const uint4*)&Wt[(size_t)(n0 + lr) * 128 + ks + lk];
        uint4 rb1 = *(const uint4*)&Wt[(size_t)(n0 + 16 + lr) * 128 + ks + lk];
        f16x8 a0 = *(f16x8*)&ra0, a1 = *(f16x8*)&ra1;
        f16x8 b0 = *(f16x8*)&rb0, b1 = *(f16x8*)&rb1;
        acc00 = __builtin_amdgcn_mfma_f32_16x16x32_f16(a0, b0, acc00, 0, 0, 0);
        acc01 = __builtin_amdgcn_mfma_f32_16x16x32_f16(a0, b1, acc01, 0, 0, 0);
        acc10 = __builtin_amdgcn_mfma_f32_16x16x32_f16(a1, b0, acc10, 0, 0, 0);
        acc11 = __builtin_amdgcn_mfma_f32_16x16x32_f16(a1, b1, acc11, 0, 0, 0);
    }
    unsigned short* ho = hout + (size_t)g * N_ * 128;
    int rbase = (lane >> 4) * 4;
#pragma unroll
    for (int r = 0; r < 4; r++) {
        int n0r = nbase + rbase + r;
        int n1r = nbase + 16 + rbase + r;
        if (n0r < N_) {
            ho[(size_t)n0r * 128 + n0 + lr]      = h1f(acc00[r]);
            ho[(size_t)n0r * 128 + n0 + 16 + lr] = h1f(acc01[r]);
        }
        if (n1r < N_) {
            ho[(size_t)n1r * 128 + n0 + lr]      = h1f(acc10[r]);
            ho[(size_t)n1r * 128 + n0 + 16 + lr] = h1f(acc11[r]);
        }
    }
    // fused alphas (heads 2*wave, 2*wave+1); 16-lane-group reductions
    float as_lo = avs[n0 + lr], as_hi = avs[n0 + 16 + lr];
    float ad_lo = avd[n0 + lr], ad_hi = avd[n0 + 16 + lr];
    float* asp = asrc + (size_t)g * N_ * HEADS_;
    float* adp = adst + (size_t)g * N_ * HEADS_;
    int h0i = 2 * wave, h1i = 2 * wave + 1;
#pragma unroll
    for (int r = 0; r < 4; r++) {
        float ps0 = acc00[r] * as_lo, ps1 = acc01[r] * as_hi;
        float pd0 = acc00[r] * ad_lo, pd1 = acc01[r] * ad_hi;
        float qs0 = acc10[r] * as_lo, qs1 = acc11[r] * as_hi;
        float qd0 = acc10[r] * ad_lo, qd1 = acc11[r] * ad_hi;
#pragma unroll
        for (int mm = 1; mm < 16; mm <<= 1) {
            ps0 += __shfl_xor(ps0, mm); ps1 += __shfl_xor(ps1, mm);
            pd0 += __shfl_xor(pd0, mm); pd1 += __shfl_xor(pd1, mm);
            qs0 += __shfl_xor(qs0, mm); qs1 += __shfl_xor(qs1, mm);
            qd0 += __shfl_xor(qd0, mm); qd1 += __shfl_xor(qd1, mm);
        }
        if (lr == 0) {
            int n0r = nbase + rbase + r;
            int n1r = nbase + 16 + rbase + r;
            if (n0r < N_) {
                asp[n0r * HEADS_ + h0i] = ps0; asp[n0r * HEADS_ + h1i] = ps1;
                adp[n0r * HEADS_ + h0i] = pd0; adp[n0r * HEADS_ + h1i] = pd1;
            }
            if (n1r < N_) {
                asp[n1r * HEADS_ + h0i] = qs0; asp[n1r * HEADS_ + h1i] = qs1;
                adp[n1r * HEADS_ + h0i] = qd0; adp[n1r * HEADS_ + h1i] = qd1;
            }
        }
    }
}

// ---------------- aggregation: ONE WAVE PER NODE; no-max softmax; f16 h (fma_mix) ----------------
__global__ __launch_bounds__(256) void gat_aggregate_both_kernel(
        const unsigned short* __restrict__ hb /*[2][N][128] f16*/,
        const float* __restrict__ asrc, const float* __restrict__ adst,
        const int* __restrict__ row_start, const int* __restrict__ sorted_src,
        void* __restrict__ out0, void* __restrict__ out1,
        unsigned* __restrict__ ng0, unsigned* __restrict__ ng1,
        int apply_elu, int out_f16) {
    int wave = threadIdx.x >> 6;
    int lane = threadIdx.x & 63;
    int idx = blockIdx.x * 4 + wave;        // [0, 2N)
    if (idx >= 2 * N_) return;
    int g = (idx >= N_);
    int node = g ? idx - N_ : idx;
    const unsigned short* hbt = hb + (size_t)g * N_ * 128;
    const float* as = asrc + (size_t)g * N_ * HEADS_;
    const float* adp = adst + (size_t)g * N_ * HEADS_;
    const int* rs = row_start + (size_t)g * (N_ + 1);
    const int* ss = sorted_src + (size_t)g * E_;

    int e8 = lane >> 3;
    int head = lane & 7;
    float ad = adp[node * HEADS_ + head];
    int beg = rs[node], end = rs[node + 1];
    float denom = 0.f;
    float acc[16];
#pragma unroll
    for (int k = 0; k < 16; k++) acc[k] = 0.f;
    int iters = (end - beg + 7) >> 3;
    for (int k = 0; k < iters; k++) {
        int i = beg + k * 8 + e8;
        if (i < end) {
            int s = ss[i];
            float e = as[s * HEADS_ + head] + ad;
            e = (e >= 0.f) ? e : ALPHA_ * e;
            const uint4* hp = (const uint4*)&hbt[(size_t)s * 128 + head * 16];
            uint4 A = hp[0], Bv = hp[1];
            float w = __expf(e);
            denom += w;
            acc[0]  += w * hlo(A.x);  acc[1]  += w * hhi(A.x);
            acc[2]  += w * hlo(A.y);  acc[3]  += w * hhi(A.y);
            acc[4]  += w * hlo(A.z);  acc[5]  += w * hhi(A.z);
            acc[6]  += w * hlo(A.w);  acc[7]  += w * hhi(A.w);
            acc[8]  += w * hlo(Bv.x); acc[9]  += w * hhi(Bv.x);
            acc[10] += w * hlo(Bv.y); acc[11] += w * hhi(Bv.y);
            acc[12] += w * hlo(Bv.z); acc[13] += w * hhi(Bv.z);
            acc[14] += w * hlo(Bv.w); acc[15] += w * hhi(Bv.w);
        }
    }
#pragma unroll
    for (int off = 8; off < 64; off <<= 1) {
        denom += __shfl_xor(denom, off);
#pragma unroll
        for (int k2 = 0; k2 < 16; k2++)
            acc[k2] += __shfl_xor(acc[k2], off);
    }
    float invd = 1.0f / fmaxf(denom, 1e-16f);
    float v0 = acc[e8 * 2] * invd;
    float v1 = acc[e8 * 2 + 1] * invd;
    if (apply_elu) {
        v0 = (v0 > 0.f) ? v0 : (__expf(v0) - 1.f);
        v1 = (v1 > 0.f) ? v1 : (__expf(v1) - 1.f);
    }
    if (out_f16) {
        unsigned* ob = (unsigned*)(g ? out1 : out0);
        ob[(size_t)node * 64 + head * 8 + e8] = pack2h(v0, v1);
    } else {
        // fused l2norm over the full 128-wide row (64 lanes x 2 elems)
        float ssum = v0 * v0 + v1 * v1;
#pragma unroll
        for (int off = 1; off < 64; off <<= 1) ssum += __shfl_xor(ssum, off);
        float inv = 1.0f / fmaxf(sqrtf(ssum), 1e-12f);
        float* of = (float*)(g ? out1 : out0);
        *(float2*)&of[(size_t)node * DIM_ + head * HD_ + e8 * 2] = make_float2(v0, v1);
        unsigned* ngp = g ? ng1 : ng0;
        ngp[(size_t)node * 64 + head * 8 + e8] = pack2h(v0 * inv, v1 * inv);
    }
}

// ---------------- l2norm + f16 pack for rel tables only ----------------
__global__ __launch_bounds__(256) void normpack_rel_kernel(
        const float* __restrict__ rel_sr, const float* __restrict__ rel_tg,
        unsigned* __restrict__ nrel_sr, unsigned* __restrict__ nrel_tg) {
    int row = blockIdx.x * 4 + (threadIdx.x >> 6);
    int lane = threadIdx.x & 63;
    const float* v; unsigned* o; int r;
    if (row < NREL_)          { v = rel_sr; o = nrel_sr; r = row; }
    else if (row < 2 * NREL_) { v = rel_tg; o = nrel_tg; r = row - NREL_; }
    else return;
    float2 a = *(const float2*)&v[(size_t)r * DIM_ + lane * 2];
    float s = a.x * a.x + a.y * a.y;
#pragma unroll
    for (int m = 1; m < 64; m <<= 1) s += __shfl_xor(s, m);
    float inv = 1.0f / fmaxf(sqrtf(s), 1e-12f);
    o[(size_t)r * 64 + lane] = pack2h(a.x * inv, a.y * inv);
}

// ---------------- TransE truth values, both graphs: 16 lanes/item, f16 rows ----------------
__global__ __launch_bounds__(256) void transe_both_kernel(
        const unsigned* __restrict__ ng0, const unsigned* __restrict__ nr0,
        const int* __restrict__ h0, const int* __restrict__ t0, const int* __restrict__ r0,
        const unsigned* __restrict__ ng1, const unsigned* __restrict__ nr1,
        const int* __restrict__ h1, const int* __restrict__ t1, const int* __restrict__ r1,
        float* __restrict__ out_tv) {   // base OFF_TV; sr items [0,2T), tg items [2T,4T)
    int gt = blockIdx.x * 256 + threadIdx.x;
    int item = gt >> 4;
    int l16 = threadIdx.x & 15;
    if (item >= 4 * T_) return;
    const unsigned *ng, *nr;
    const int *hi, *ti, *ri;
    int k;
    if (item < 2 * T_) { ng = ng0; nr = nr0; hi = h0; ti = t0; ri = r0; k = item; }
    else               { ng = ng1; nr = nr1; hi = h1; ti = t1; ri = r1; k = item - 2 * T_; }
    int hh = hi[k], tt = ti[k], rr = ri[k];
    const uint4* ph = (const uint4*)&ng[(size_t)hh * 64 + l16 * 4];
    const uint4* pt = (const uint4*)&ng[(size_t)tt * 64 + l16 * 4];
    const uint4* pr = (const uint4*)&nr[(size_t)rr * 64 + l16 * 4];
    uint4 H = ph[0], Tt = pt[0], Rr = pr[0];
    float s = 0.f;
    s += fabsf(hlo(H.x) + hlo(Rr.x) - hlo(Tt.x));
    s += fabsf(hhi(H.x) + hhi(Rr.x) - hhi(Tt.x));
    s += fabsf(hlo(H.y) + hlo(Rr.y) - hlo(Tt.y));
    s += fabsf(hhi(H.y) + hhi(Rr.y) - hhi(Tt.y));
    s += fabsf(hlo(H.z) + hlo(Rr.z) - hlo(Tt.z));
    s += fabsf(hhi(H.z) + hhi(Rr.z) - hhi(Tt.z));
    s += fabsf(hlo(H.w) + hlo(Rr.w) - hlo(Tt.w));
    s += fabsf(hhi(H.w) + hhi(Rr.w) - hhi(Tt.w));
#pragma unroll
    for (int m = 1; m < 16; m <<= 1) s += __shfl_xor(s, m);
    if (l16 == 0) out_tv[item] = 1.0f - s * INV3SQRT_;
}

// ---------------- rule grounding, both graphs (f16 rows) ----------------
__global__ __launch_bounds__(256) void rule_both_kernel(
        const unsigned* __restrict__ ng0, const unsigned* __restrict__ nr0,
        const int* __restrict__ rh0, const int* __restrict__ rt0, const int* __restrict__ rr0,
        const int* __restrict__ prem0, const float* __restrict__ tvcol0,
        const unsigned* __restrict__ ng1, const unsigned* __restrict__ nr1,
        const int* __restrict__ rh1, const int* __restrict__ rt1, const int* __restrict__ rr1,
        const int* __restrict__ prem1, const float* __restrict__ tvcol1,
        float* __restrict__ out_rule) {  // base OFF_RULE; sr [0,R), tg [R,2R)
    int gt = blockIdx.x * 256 + threadIdx.x;
    int item = gt >> 4;
    int l16 = threadIdx.x & 15;
    if (item >= 2 * R_) return;
    const unsigned *ng, *nr;
    const int *rh, *rt, *rr, *prem;
    const float* tvcol;
    int k;
    if (item < R_) { ng = ng0; nr = nr0; rh = rh0; rt = rt0; rr = rr0; prem = prem0; tvcol = tvcol0; k = item; }
    else           { ng = ng1; nr = nr1; rh = rh1; rt = rt1; rr = rr1; prem = prem1; tvcol = tvcol1; k = item - R_; }
    int hh = rh[k], tt = rt[k], rx = rr[k];
    const uint4* ph = (const uint4*)&ng[(size_t)hh * 64 + l16 * 4];
    const uint4* pt = (const uint4*)&ng[(size_t)tt * 64 + l16 * 4];
    const uint4* pr = (const uint4*)&nr[(size_t)rx * 64 + l16 * 4];
    uint4 H = ph[0], Tt = pt[0], Rr = pr[0];
    float s = 0.f;
    s += fabsf(hlo(H.x) + hlo(Rr.x) - hlo(Tt.x));
    s += fabsf(hhi(H.x) + hhi(Rr.x) - hhi(Tt.x));
    s += fabsf(hlo(H.y) + hlo(Rr.y) - hlo(Tt.y));
    s += fabsf(hhi(H.y) + hhi(Rr.y) - hhi(Tt.y));
    s += fabsf(hlo(H.z) + hlo(Rr.z) - hlo(Tt.z));
    s += fabsf(hhi(H.z) + hhi(Rr.z) - hhi(Tt.z));
    s += fabsf(hlo(H.w) + hlo(Rr.w) - hlo(Tt.w));
    s += fabsf(hhi(H.w) + hhi(Rr.w) - hhi(Tt.w));
#pragma unroll
    for (int m = 1; m < 16; m <<= 1) s += __shfl_xor(s, m);
    if (l16 == 0) {
        float rs = 1.0f - s * INV3SQRT_;
        int p0 = prem[k * 2], p1 = prem[k * 2 + 1];
        float f1 = (p0 < T_) ? tvcol[(size_t)p0 * 2] : 1.0f;
        float f2 = (p1 < T_) ? tvcol[(size_t)p1 * 2] : 1.0f;
        out_rule[item] = 1.0f + f1 * f2 * (rs - 1.0f);
    }
}

// ---------------- output gather, both graphs ----------------
__global__ __launch_bounds__(256) void gather_both_kernel(
        const float* __restrict__ g0, const int* __restrict__ data0,
        const float* __restrict__ g1, const int* __restrict__ data1,
        float* __restrict__ out) {  // sr at [0, B*DIM), tg at [B*DIM, 2*B*DIM)
    int i = blockIdx.x * 256 + threadIdx.x;
    if (i >= 2 * B_ * DIM_) return;
    const float* g = (i < B_ * DIM_) ? g0 : g1;
    const int* data = (i < B_ * DIM_) ? data0 : data1;
    int j = (i < B_ * DIM_) ? i : i - B_ * DIM_;
    int r = j >> 7, o = j & 127;
    out[i] = g[(size_t)data[r] * DIM_ + o];
}

// ---------------- launch ----------------

extern "C" void kernel_launch(void* const* d_in, const int* in_sizes, int n_in,
                              void* d_out, int out_size, void* d_ws, size_t ws_size,
                              hipStream_t stream) {
    const float* ent_sr = (const float*)d_in[0];
    const float* ent_tg = (const float*)d_in[1];
    const float* rel_sr = (const float*)d_in[2];
    const float* rel_tg = (const float*)d_in[3];
    const float* gat_W  = (const float*)d_in[4];
    const float* a_src  = (const float*)d_in[5];
    const float* a_dst  = (const float*)d_in[6];
    const int* sr_data  = (const int*)d_in[7];
    const int* tg_data  = (const int*)d_in[8];
    const int* edges_sr = (const int*)d_in[9];
    const int* edges_tg = (const int*)d_in[10];
    const int* h_sr = (const int*)d_in[11];
    const int* t_sr = (const int*)d_in[12];
    const int* r_sr = (const int*)d_in[13];
    const int* h_tg = (const int*)d_in[14];
    const int* t_tg = (const int*)d_in[15];
    const int* r_tg = (const int*)d_in[16];
    const int* rh_sr = (const int*)d_in[17];
    const int* rt_sr = (const int*)d_in[18];
    const int* rr_sr = (const int*)d_in[19];
    const int* prem_sr = (const int*)d_in[20];
    const int* rh_tg = (const int*)d_in[21];
    const int* rt_tg = (const int*)d_in[22];
    const int* rr_tg = (const int*)d_in[23];
    const int* prem_tg = (const int*)d_in[24];

    float* out = (float*)d_out;

    // workspace layout
    size_t off = 0;
    auto alloc = [&](size_t bytes) {
        void* p = (char*)d_ws + off;
        off += (bytes + 255) & ~(size_t)255;
        return p;
    };
    float* g_sr   = (float*)alloc((size_t)N_ * DIM_ * 4);
    float* g_tg   = (float*)alloc((size_t)N_ * DIM_ * 4);
    unsigned short* hb_buf = (unsigned short*)alloc((size_t)2 * N_ * 128 * 2); // [2][N][128] f16
    unsigned* x2b = (unsigned*)alloc((size_t)2 * N_ * 64 * 4);                 // [2][N][64] f16 pairs
    float* asrc_b = (float*)alloc((size_t)2 * N_ * HEADS_ * 4);
    float* adst_b = (float*)alloc((size_t)2 * N_ * HEADS_ * 4);
    unsigned* ng_sr = (unsigned*)alloc((size_t)N_ * 64 * 4);
    unsigned* ng_tg = (unsigned*)alloc((size_t)N_ * 64 * 4);
    unsigned* nrel_sr = (unsigned*)alloc((size_t)NREL_ * 64 * 4);
    unsigned* nrel_tg = (unsigned*)alloc((size_t)NREL_ * 64 * 4);
    int* sorted_src = (int*)alloc((size_t)2 * E_ * 4);
    int* row_start  = (int*)alloc((size_t)2 * (N_ + 1) * 4);
    int* slab       = (int*)alloc((size_t)2 * E_ * 4);
    int* cmat       = (int*)alloc((size_t)2 * NB_ * NBLK4_ * 4);
    int* tot        = (int*)alloc((size_t)2 * NB_ * 4);
    int* bbase      = (int*)alloc((size_t)2 * (NB_ + 1) * 4);
    unsigned short* Wt = (unsigned short*)alloc((size_t)2 * 128 * 128 * 2);    // [2][o][k] f16

    const float* as0 = a_src;        const float* as1 = a_src + HEADS_ * HD_;
    const float* ad0 = a_dst;        const float* ad1 = a_dst + HEADS_ * HD_;

    const size_t OFF_G_TG  = (size_t)B_ * DIM_;        // 1,280,000
    const size_t OFF_TV    = (size_t)2 * B_ * DIM_;    // 2,560,000
    const size_t OFF_RULE  = OFF_TV + (size_t)4 * T_;  // 3,360,000

    const int GEMM_GRID = (N_ + 31) / 32;              // 1563
    const int AGG_GRID  = (2 * N_ + 3) / 4;

    const int* esrc_sr = edges_sr;          const int* edst_sr = edges_sr + E_;
    const int* esrc_tg = edges_tg;          const int* edst_tg = edges_tg + E_;
    unsigned* x2b_sr = x2b;                 unsigned* x2b_tg = x2b + (size_t)N_ * 64;

    // ---- prep: W -> Wt f16 (both layers) ----
    prep_wt_kernel<<<(2 * 128 * 128 + 255) / 256, 256, 0, stream>>>(gat_W, Wt);

    // ---- radix partition by dst bucket, both graphs ----
    count_mat_kernel<<<2 * NBLK_, 256, 0, stream>>>(edst_sr, edst_tg, cmat);
    rowsum_kernel<<<2 * NB_, 256, 0, stream>>>(cmat, tot);
    bucket_scan_kernel<<<1, 1024, 0, stream>>>(tot, bbase, row_start);
    rowscan_kernel<<<2 * NB_, 256, 0, stream>>>(bbase, cmat);
    part_scatter_kernel<<<2 * NBLK_, 256, 0, stream>>>(
        esrc_sr, edst_sr, esrc_tg, edst_tg, cmat, slab);
    bucket_sort_kernel<<<2 * NB_, 256, 0, stream>>>(bbase, slab, row_start, sorted_src);

    // ---- GAT layer 0 (gemm+alphas fused) ----
    gemm_mfma_both_kernel<<<2 * GEMM_GRID, 256, 0, stream>>>(
        ent_sr, ent_tg, 1, Wt, as0, ad0, hb_buf, asrc_b, adst_b, GEMM_GRID);
    gat_aggregate_both_kernel<<<AGG_GRID, 256, 0, stream>>>(
        hb_buf, asrc_b, adst_b, row_start, sorted_src, x2b_sr, x2b_tg,
        (unsigned*)nullptr, (unsigned*)nullptr, 1, 1);
    // ---- GAT layer 1 (gemm+alphas fused; aggregate fuses g-l2norm + ng pack) ----
    gemm_mfma_both_kernel<<<2 * GEMM_GRID, 256, 0, stream>>>(
        x2b_sr, x2b_tg, 0, Wt + 128 * 128, as1, ad1, hb_buf, asrc_b, adst_b, GEMM_GRID);
    gat_aggregate_both_kernel<<<AGG_GRID, 256, 0, stream>>>(
        hb_buf, asrc_b, adst_b, row_start, sorted_src, g_sr, g_tg,
        ng_sr, ng_tg, 0, 0);

    // ---- l2norm + f16 pack for rel only ----
    normpack_rel_kernel<<<(2 * NREL_ + 3) / 4, 256, 0, stream>>>(
        rel_sr, rel_tg, nrel_sr, nrel_tg);

    // ---- TransE tv ----
    transe_both_kernel<<<(4 * T_ * 16 + 255) / 256, 256, 0, stream>>>(
        ng_sr, nrel_sr, h_sr, t_sr, r_sr,
        ng_tg, nrel_tg, h_tg, t_tg, r_tg,
        out + OFF_TV);

    // ---- rules ----
    rule_both_kernel<<<(2 * R_ * 16 + 255) / 256, 256, 0, stream>>>(
        ng_sr, nrel_sr, rh_sr, rt_sr, rr_sr, prem_sr, out + OFF_TV + 0,
        ng_tg, nrel_tg, rh_tg, rt_tg, rr_tg, prem_tg, out + OFF_TV + (size_t)2 * T_ + 1,
        out + OFF_RULE);

    // ---- gathers ----
    gather_both_kernel<<<(2 * B_ * DIM_ + 255) / 256, 256, 0, stream>>>(
        g_sr, sr_data, g_tg, tg_data, out);
}